// Round 2
// baseline (3216.835 us; speedup 1.0000x reference)
//
#include <hip/hip_runtime.h>

#define Nx 2048
#define DIMx 512
#define Hx 8
#define DHx 64
#define CTXx 2049
#define SCALEx 0.125f

// ---------------- LayerNorm: one block per row of 512 ----------------
__global__ void __launch_bounds__(256) ln_kernel(const float* __restrict__ x,
                                                 const float* __restrict__ gamma,
                                                 float* __restrict__ out){
    int row = blockIdx.x;
    int t   = threadIdx.x;
    const float* xr = x + (size_t)row * DIMx;
    float a = xr[t], b = xr[t + 256];
    __shared__ float rs[256], rq[256];
    rs[t] = a + b; rq[t] = a * a + b * b;
    __syncthreads();
    #pragma unroll
    for (int off = 128; off > 0; off >>= 1){
        if (t < off){ rs[t] += rs[t + off]; rq[t] += rq[t + off]; }
        __syncthreads();
    }
    float mu  = rs[0] * (1.f / DIMx);
    float var = fmaxf(rq[0] * (1.f / DIMx) - mu * mu, 0.f);
    float r   = rsqrtf(var + 1e-5f);
    float* orow = out + (size_t)row * DIMx;
    orow[t]       = (a - mu) * r * gamma[t];
    orow[t + 256] = (b - mu) * r * gamma[t + 256];
}

// ---------------- null K/V row fill ----------------
__global__ void nullkv_kernel(const float* __restrict__ nkv,
                              float* __restrict__ kb, float* __restrict__ vb){
    int t = threadIdx.x;            // 256 = 4 batches * 64 dims
    int b = t >> 6, d = t & 63;
    kb[(size_t)b * CTXx * DHx + d] = nkv[d];
    vb[(size_t)b * CTXx * DHx + d] = nkv[DHx + d];
}

// ---------------- fused QKV projection: C(8192x640) = xn(8192x512) @ [Wq|Wkv] ----------------
__global__ void __launch_bounds__(256) gemm_qkv(const float* __restrict__ xn,
                                                const float* __restrict__ Wq,
                                                const float* __restrict__ Wkv,
                                                float* __restrict__ qb,
                                                float* __restrict__ kb,
                                                float* __restrict__ vb){
    __shared__ float As[32][68];
    __shared__ float Bs[32][68];
    int t  = threadIdx.x;
    int tx = t & 15, ty = t >> 4;
    int row0 = blockIdx.y * 64, col0 = blockIdx.x * 64;
    float acc[4][4] = {};
    int mA = t >> 2, kA0 = (t & 3) * 8;
    int kB = t >> 3, cB0 = (t & 7) * 8;
    int colB = col0 + cB0;
    const float* aSrc = xn + (size_t)(row0 + mA) * DIMx + kA0;
    const float* bSrc = (colB < 512) ? (Wq  + (size_t)kB * 512 + colB)
                                     : (Wkv + (size_t)kB * 128 + (colB - 512));
    size_t bStride = (colB < 512) ? 512 : 128;
    for (int k0 = 0; k0 < DIMx; k0 += 32){
        float4 a0 = *(const float4*)(aSrc + k0);
        float4 a1 = *(const float4*)(aSrc + k0 + 4);
        float4 b0 = *(const float4*)(bSrc + (size_t)k0 * bStride);
        float4 b1 = *(const float4*)(bSrc + (size_t)k0 * bStride + 4);
        As[kA0 + 0][mA] = a0.x; As[kA0 + 1][mA] = a0.y;
        As[kA0 + 2][mA] = a0.z; As[kA0 + 3][mA] = a0.w;
        As[kA0 + 4][mA] = a1.x; As[kA0 + 5][mA] = a1.y;
        As[kA0 + 6][mA] = a1.z; As[kA0 + 7][mA] = a1.w;
        Bs[kB][cB0 + 0] = b0.x; Bs[kB][cB0 + 1] = b0.y;
        Bs[kB][cB0 + 2] = b0.z; Bs[kB][cB0 + 3] = b0.w;
        Bs[kB][cB0 + 4] = b1.x; Bs[kB][cB0 + 5] = b1.y;
        Bs[kB][cB0 + 6] = b1.z; Bs[kB][cB0 + 7] = b1.w;
        __syncthreads();
        #pragma unroll
        for (int kk = 0; kk < 32; kk++){
            float4 a4 = *(const float4*)&As[kk][ty * 4];
            float4 b4 = *(const float4*)&Bs[kk][tx * 4];
            float av[4] = {a4.x, a4.y, a4.z, a4.w};
            float bv[4] = {b4.x, b4.y, b4.z, b4.w};
            #pragma unroll
            for (int i = 0; i < 4; i++)
                #pragma unroll
                for (int j = 0; j < 4; j++)
                    acc[i][j] = fmaf(av[i], bv[j], acc[i][j]);
        }
        __syncthreads();
    }
    #pragma unroll
    for (int i = 0; i < 4; i++){
        int r  = row0 + ty * 4 + i;
        int bb = r >> 11, ii = r & 2047;
        #pragma unroll
        for (int j = 0; j < 4; j++){
            int col = col0 + tx * 4 + j;
            float v = acc[i][j];
            if (col < 512)      qb[(size_t)r * 512 + col] = v * SCALEx;
            else if (col < 576) kb[((size_t)bb * CTXx + ii + 1) * DHx + (col - 512)] = v;
            else                vb[((size_t)bb * CTXx + ii + 1) * DHx + (col - 576)] = v;
        }
    }
}

// ---------------- output projection: z(8192x512) = ob(8192x512) @ Wout ----------------
__global__ void __launch_bounds__(256) gemm_out(const float* __restrict__ a,
                                                const float* __restrict__ w,
                                                float* __restrict__ z){
    __shared__ float As[32][68];
    __shared__ float Bs[32][68];
    int t  = threadIdx.x;
    int tx = t & 15, ty = t >> 4;
    int row0 = blockIdx.y * 64, col0 = blockIdx.x * 64;
    float acc[4][4] = {};
    int mA = t >> 2, kA0 = (t & 3) * 8;
    int kB = t >> 3, cB0 = (t & 7) * 8;
    const float* aSrc = a + (size_t)(row0 + mA) * 512 + kA0;
    const float* bSrc = w + (size_t)kB * 512 + col0 + cB0;
    for (int k0 = 0; k0 < 512; k0 += 32){
        float4 a0 = *(const float4*)(aSrc + k0);
        float4 a1 = *(const float4*)(aSrc + k0 + 4);
        float4 b0 = *(const float4*)(bSrc + (size_t)k0 * 512);
        float4 b1 = *(const float4*)(bSrc + (size_t)k0 * 512 + 4);
        As[kA0 + 0][mA] = a0.x; As[kA0 + 1][mA] = a0.y;
        As[kA0 + 2][mA] = a0.z; As[kA0 + 3][mA] = a0.w;
        As[kA0 + 4][mA] = a1.x; As[kA0 + 5][mA] = a1.y;
        As[kA0 + 6][mA] = a1.z; As[kA0 + 7][mA] = a1.w;
        Bs[kB][cB0 + 0] = b0.x; Bs[kB][cB0 + 1] = b0.y;
        Bs[kB][cB0 + 2] = b0.z; Bs[kB][cB0 + 3] = b0.w;
        Bs[kB][cB0 + 4] = b1.x; Bs[kB][cB0 + 5] = b1.y;
        Bs[kB][cB0 + 6] = b1.z; Bs[kB][cB0 + 7] = b1.w;
        __syncthreads();
        #pragma unroll
        for (int kk = 0; kk < 32; kk++){
            float4 a4 = *(const float4*)&As[kk][ty * 4];
            float4 b4 = *(const float4*)&Bs[kk][tx * 4];
            float av[4] = {a4.x, a4.y, a4.z, a4.w};
            float bv[4] = {b4.x, b4.y, b4.z, b4.w};
            #pragma unroll
            for (int i = 0; i < 4; i++)
                #pragma unroll
                for (int j = 0; j < 4; j++)
                    acc[i][j] = fmaf(av[i], bv[j], acc[i][j]);
        }
        __syncthreads();
    }
    #pragma unroll
    for (int i = 0; i < 4; i++){
        int r = row0 + ty * 4 + i;
        #pragma unroll
        for (int j = 0; j < 4; j++){
            int col = col0 + tx * 4 + j;
            z[(size_t)r * 512 + col] = acc[i][j];
        }
    }
}

// ---------------- attention: block = 4 waves, wave = 8 q-rows, tiles of 64 keys ----------------
// No-running-max softmax: |scores| bounded ~2 (q pre-scaled by 0.125); fminf clamp is
// diagnostics-insurance only (turns dtype bugs into finite garbage instead of NaN).
__global__ void __launch_bounds__(256) attn_kernel(const float* __restrict__ qb,
                                                   const float* __restrict__ kb,
                                                   const float* __restrict__ vb,
                                                   const int* __restrict__ mask,
                                                   float* __restrict__ ob){
    __shared__ float4 ks4[64][17];   // [key][dim/4]
    __shared__ float4 vs4[64][17];   // [dim][key/4]  (transposed)
    __shared__ float4 qs4[32][17];   // [row][dim/4]
    __shared__ float4 ps4[32][17];   // [row][key/4]
    float* kf = (float*)ks4; float* vf = (float*)vs4;
    float* qf = (float*)qs4; float* pf = (float*)ps4;
    int t = threadIdx.x;
    int lane = t & 63, w = t >> 6;
    int i0 = blockIdx.x * 32, h = blockIdx.y, b = blockIdx.z;
    const int* mrow = mask + b * Nx;
    // stage Q (32 rows x 64 dims)
    {
        int r = t >> 3, d0 = (t & 7) * 8;
        const float* src = qb + ((size_t)(b * Nx + i0 + r)) * 512 + h * DHx + d0;
        float4 q0 = *(const float4*)(src);
        float4 q1 = *(const float4*)(src + 4);
        float* dst = qf + r * 68 + d0;
        dst[0] = q0.x; dst[1] = q0.y; dst[2] = q0.z; dst[3] = q0.w;
        dst[4] = q1.x; dst[5] = q1.y; dst[6] = q1.z; dst[7] = q1.w;
    }
    float o_acc[8], l_lane[8];
    #pragma unroll
    for (int r = 0; r < 8; r++){ o_acc[r] = 0.f; l_lane[r] = 0.f; }
    int r0 = w * 8;
    for (int j0 = 0; j0 < CTXx; j0 += 64){
        __syncthreads();   // previous tile consumed (covers Q staging on first iter)
        // stage K,V tile (64 keys x 64 dims each)
        #pragma unroll
        for (int i = 0; i < 2; i++){
            int l  = i * 32 + (t >> 3);
            int d0 = (t & 7) * 8;
            int jk = j0 + l;
            float kv[8], vv[8];
            if (jk < CTXx){
                const float* ksrc = kb + ((size_t)b * CTXx + jk) * DHx + d0;
                const float* vsrc = vb + ((size_t)b * CTXx + jk) * DHx + d0;
                float4 k0v = *(const float4*)(ksrc);
                float4 k1v = *(const float4*)(ksrc + 4);
                float4 v0v = *(const float4*)(vsrc);
                float4 v1v = *(const float4*)(vsrc + 4);
                kv[0]=k0v.x; kv[1]=k0v.y; kv[2]=k0v.z; kv[3]=k0v.w;
                kv[4]=k1v.x; kv[5]=k1v.y; kv[6]=k1v.z; kv[7]=k1v.w;
                vv[0]=v0v.x; vv[1]=v0v.y; vv[2]=v0v.z; vv[3]=v0v.w;
                vv[4]=v1v.x; vv[5]=v1v.y; vv[6]=v1v.z; vv[7]=v1v.w;
            } else {
                #pragma unroll
                for (int jj = 0; jj < 8; jj++){ kv[jj] = 0.f; vv[jj] = 0.f; }
            }
            #pragma unroll
            for (int jj = 0; jj < 8; jj++){
                kf[l * 68 + d0 + jj]   = kv[jj];
                vf[(d0 + jj) * 68 + l] = vv[jj];
            }
        }
        __syncthreads();
        // scores: lane = key, 8 rows per wave
        float sc[8];
        #pragma unroll
        for (int r = 0; r < 8; r++) sc[r] = 0.f;
        #pragma unroll
        for (int dc = 0; dc < 16; dc++){
            float4 k4 = ks4[lane][dc];
            #pragma unroll
            for (int r = 0; r < 8; r++){
                float4 q4 = qs4[r0 + r][dc];
                sc[r] = fmaf(q4.x, k4.x, fmaf(q4.y, k4.y, fmaf(q4.z, k4.z, fmaf(q4.w, k4.w, sc[r]))));
            }
        }
        int jk = j0 + lane;
        bool valid = (jk < CTXx) && (jk == 0 || mrow[jk - 1] != 0);
        #pragma unroll
        for (int r = 0; r < 8; r++){
            float p = valid ? __expf(fminf(sc[r], 60.f)) : 0.f;
            l_lane[r] += p;
            pf[(r0 + r) * 68 + lane] = p;
        }
        __syncthreads();
        // PV: lane = dim
        #pragma unroll
        for (int lc = 0; lc < 16; lc++){
            float4 v4 = vs4[lane][lc];
            #pragma unroll
            for (int r = 0; r < 8; r++){
                float4 p4 = ps4[r0 + r][lc];
                o_acc[r] = fmaf(p4.x, v4.x, fmaf(p4.y, v4.y, fmaf(p4.z, v4.z, fmaf(p4.w, v4.w, o_acc[r]))));
            }
        }
    }
    #pragma unroll
    for (int r = 0; r < 8; r++){
        float l = l_lane[r];
        #pragma unroll
        for (int off = 32; off > 0; off >>= 1) l += __shfl_xor(l, off, 64);
        o_acc[r] /= fmaxf(l, 1e-20f);
    }
    #pragma unroll
    for (int r = 0; r < 8; r++)
        ob[((size_t)b * Nx + i0 + r0 + r) * 512 + h * DHx + lane] = o_acc[r];
}

extern "C" void kernel_launch(void* const* d_in, const int* in_sizes, int n_in,
                              void* d_out, int out_size, void* d_ws, size_t ws_size,
                              hipStream_t stream){
    const float* x     = (const float*)d_in[0];
    const int*   mask  = (const int*)  d_in[1];
    const float* gamma = (const float*)d_in[2];
    const float* Wq    = (const float*)d_in[3];
    const float* Wkv   = (const float*)d_in[4];
    const float* nkv   = (const float*)d_in[5];
    const float* Wout  = (const float*)d_in[6];
    const float* og    = (const float*)d_in[7];
    float* out = (float*)d_out;

    float* xn = (float*)d_ws;
    float* qb = xn + (size_t)8192 * 512;
    float* kb = qb + (size_t)8192 * 512;
    float* vb = kb + (size_t)4 * CTXx * DHx;
    float* ob = xn;   // alias: xn dead after gemm_qkv completes (stream-ordered)
    float* zb = qb;   // alias: qb dead after attn_kernel completes

    ln_kernel   <<<8192, 256, 0, stream>>>(x, gamma, xn);
    nullkv_kernel<<<1, 256, 0, stream>>>(nkv, kb, vb);
    gemm_qkv    <<<dim3(10, 128), 256, 0, stream>>>(xn, Wq, Wkv, qb, kb, vb);
    attn_kernel <<<dim3(64, 8, 4), 256, 0, stream>>>(qb, kb, vb, mask, ob);
    gemm_out    <<<dim3(8, 128), 256, 0, stream>>>(ob, Wout, zb);
    ln_kernel   <<<8192, 256, 0, stream>>>(zb, og, out);
}

// Round 3
// 233.425 us; speedup vs baseline: 13.7810x; 13.7810x over previous
//
#include <hip/hip_runtime.h>

typedef __attribute__((ext_vector_type(8))) short bf16x8;   // 8 bf16 = 4 VGPRs (MFMA A/B frag)
typedef __attribute__((ext_vector_type(4))) float f32x4;    // MFMA C/D frag
typedef __attribute__((ext_vector_type(2))) short short2v;

#define Nx 2048
#define CTXx 2049
#define QSCALE 0.125f

__device__ __forceinline__ short f2bs(float x){   // float -> bf16 bits (RNE)
    unsigned u = __builtin_bit_cast(unsigned, x);
    u = (u + 0x7fffu + ((u >> 16) & 1u)) >> 16;
    return (short)u;
}

// ---------------- LN1: fp32 in -> bf16 out, wave per row ----------------
__global__ void __launch_bounds__(256) ln1_kernel(const float* __restrict__ x,
                                                  const float* __restrict__ g,
                                                  short* __restrict__ out){
    int w = threadIdx.x >> 6, lane = threadIdx.x & 63;
    size_t row = (size_t)blockIdx.x * 4 + w;
    const float* xr = x + row * 512 + lane * 8;
    float4 a = *(const float4*)xr;
    float4 b = *(const float4*)(xr + 4);
    float s = a.x + a.y + a.z + a.w + b.x + b.y + b.z + b.w;
    float q = a.x*a.x + a.y*a.y + a.z*a.z + a.w*a.w
            + b.x*b.x + b.y*b.y + b.z*b.z + b.w*b.w;
    #pragma unroll
    for (int m = 1; m < 64; m <<= 1){ s += __shfl_xor(s, m, 64); q += __shfl_xor(q, m, 64); }
    float mu  = s * (1.f / 512.f);
    float var = fmaxf(q * (1.f / 512.f) - mu * mu, 0.f);
    float r   = rsqrtf(var + 1e-5f);
    const float* gr = g + lane * 8;
    float4 g0 = *(const float4*)gr;
    float4 g1 = *(const float4*)(gr + 4);
    bf16x8 o;
    o[0] = f2bs((a.x - mu) * r * g0.x); o[1] = f2bs((a.y - mu) * r * g0.y);
    o[2] = f2bs((a.z - mu) * r * g0.z); o[3] = f2bs((a.w - mu) * r * g0.w);
    o[4] = f2bs((b.x - mu) * r * g1.x); o[5] = f2bs((b.y - mu) * r * g1.y);
    o[6] = f2bs((b.z - mu) * r * g1.z); o[7] = f2bs((b.w - mu) * r * g1.w);
    *(bf16x8*)(out + row * 512 + lane * 8) = o;
}

// ---------------- LN2: fp32 in -> fp32 out, wave per row ----------------
__global__ void __launch_bounds__(256) ln2_kernel(const float* __restrict__ z,
                                                  const float* __restrict__ g,
                                                  float* __restrict__ out){
    int w = threadIdx.x >> 6, lane = threadIdx.x & 63;
    size_t row = (size_t)blockIdx.x * 4 + w;
    const float* xr = z + row * 512 + lane * 8;
    float4 a = *(const float4*)xr;
    float4 b = *(const float4*)(xr + 4);
    float s = a.x + a.y + a.z + a.w + b.x + b.y + b.z + b.w;
    float q = a.x*a.x + a.y*a.y + a.z*a.z + a.w*a.w
            + b.x*b.x + b.y*b.y + b.z*b.z + b.w*b.w;
    #pragma unroll
    for (int m = 1; m < 64; m <<= 1){ s += __shfl_xor(s, m, 64); q += __shfl_xor(q, m, 64); }
    float mu  = s * (1.f / 512.f);
    float var = fmaxf(q * (1.f / 512.f) - mu * mu, 0.f);
    float r   = rsqrtf(var + 1e-5f);
    const float* gr = g + lane * 8;
    float4 g0 = *(const float4*)gr;
    float4 g1 = *(const float4*)(gr + 4);
    float4 o0, o1;
    o0.x = (a.x - mu) * r * g0.x; o0.y = (a.y - mu) * r * g0.y;
    o0.z = (a.z - mu) * r * g0.z; o0.w = (a.w - mu) * r * g0.w;
    o1.x = (b.x - mu) * r * g1.x; o1.y = (b.y - mu) * r * g1.y;
    o1.z = (b.z - mu) * r * g1.z; o1.w = (b.w - mu) * r * g1.w;
    float* op = out + row * 512 + lane * 8;
    *(float4*)op = o0; *(float4*)(op + 4) = o1;
}

// ---------------- weight converts (fp32 -> bf16, once per launch) ----------------
__global__ void convert_wcat(const float* __restrict__ Wq, const float* __restrict__ Wkv,
                             short* __restrict__ Wcat){
    int r = blockIdx.x, c = threadIdx.x;          // block=320 threads, 2 cols each
    float v0 = (c < 512) ? Wq[(size_t)r * 512 + c] : Wkv[(size_t)r * 128 + c - 512];
    int c1 = c + 320;
    float v1 = (c1 < 512) ? Wq[(size_t)r * 512 + c1] : Wkv[(size_t)r * 128 + c1 - 512];
    Wcat[(size_t)r * 640 + c]  = f2bs(v0);
    Wcat[(size_t)r * 640 + c1] = f2bs(v1);
}
__global__ void convert_wout(const float* __restrict__ Wout, short* __restrict__ Woutb){
    int i = blockIdx.x * 256 + threadIdx.x;
    Woutb[i] = f2bs(Wout[i]);
}
__global__ void nullkv_kernel(const float* __restrict__ nkv,
                              short* __restrict__ kb, short* __restrict__ vb){
    int t = threadIdx.x, b = t >> 6, d = t & 63;
    kb[(size_t)b * CTXx * 64 + d] = f2bs(nkv[d]);
    vb[(size_t)b * CTXx * 64 + d] = f2bs(nkv[64 + d]);
}

// ---------------- MFMA GEMM: 128x128 tile, BK=64, 4 waves 2x2 ----------------
// MODE 0: C = xn @ [Wq|Wkv] (N=640): q-scale + k/v ctx-scatter epilogue, bf16 out
// MODE 1: C = ob @ Wout (N=512): fp32 out
template<int MODE>
__global__ void __launch_bounds__(256, 2) gemm_mfma(const short* __restrict__ A,
                                                    const short* __restrict__ Bw, int ldb,
                                                    short* __restrict__ qb,
                                                    short* __restrict__ kb,
                                                    short* __restrict__ vb,
                                                    float* __restrict__ C){
    __shared__ short As[128][72];   // [m][k], BK=64 (+8 pad)
    __shared__ short Bs[128][72];   // [n][k] (transposed)
    int t = threadIdx.x;
    int lane = t & 63, w = t >> 6;
    int l16 = lane & 15, quad = lane >> 4;
    int wm = w & 1, wn = w >> 1;
    int row0 = blockIdx.y * 128, col0 = blockIdx.x * 128;
    f32x4 acc[4][4];
    #pragma unroll
    for (int i = 0; i < 4; i++)
        #pragma unroll
        for (int j = 0; j < 4; j++) acc[i][j] = (f32x4){0.f, 0.f, 0.f, 0.f};
    int ar = t >> 1, ak = (t & 1) * 32;
    int bk = (t >> 4) * 2, bn0 = (t & 15) * 8;
    for (int k0 = 0; k0 < 512; k0 += 64){
        __syncthreads();
        {   // A staging: 32 elts/thread, 4x b128
            const short* ap = A + (size_t)(row0 + ar) * 512 + k0 + ak;
            int4 a0 = *(const int4*)(ap);
            int4 a1 = *(const int4*)(ap + 8);
            int4 a2 = *(const int4*)(ap + 16);
            int4 a3 = *(const int4*)(ap + 24);
            *(int4*)&As[ar][ak]      = a0;
            *(int4*)&As[ar][ak + 8]  = a1;
            *(int4*)&As[ar][ak + 16] = a2;
            *(int4*)&As[ar][ak + 24] = a3;
        }
        #pragma unroll
        for (int u = 0; u < 2; u++){   // B staging: transpose via short2 pair-writes
            int kk = bk + u * 32;
            const short* bp = Bw + (size_t)(k0 + kk) * ldb + col0 + bn0;
            int4 r0 = *(const int4*)bp;
            int4 r1 = *(const int4*)(bp + ldb);
            const short* s0 = (const short*)&r0;
            const short* s1 = (const short*)&r1;
            #pragma unroll
            for (int i = 0; i < 8; i++){
                short2v pr; pr[0] = s0[i]; pr[1] = s1[i];
                *(short2v*)&Bs[bn0 + i][kk] = pr;
            }
        }
        __syncthreads();
        #pragma unroll
        for (int ks = 0; ks < 2; ks++){
            bf16x8 af[4], bfr[4];
            #pragma unroll
            for (int mt = 0; mt < 4; mt++)
                af[mt] = *(const bf16x8*)&As[wm * 64 + mt * 16 + l16][ks * 32 + quad * 8];
            #pragma unroll
            for (int nt = 0; nt < 4; nt++)
                bfr[nt] = *(const bf16x8*)&Bs[wn * 64 + nt * 16 + l16][ks * 32 + quad * 8];
            #pragma unroll
            for (int mt = 0; mt < 4; mt++)
                #pragma unroll
                for (int nt = 0; nt < 4; nt++)
                    acc[mt][nt] = __builtin_amdgcn_mfma_f32_16x16x32_bf16(af[mt], bfr[nt], acc[mt][nt], 0, 0, 0);
        }
    }
    #pragma unroll
    for (int mt = 0; mt < 4; mt++)
        #pragma unroll
        for (int nt = 0; nt < 4; nt++)
            #pragma unroll
            for (int r = 0; r < 4; r++){
                int row = row0 + wm * 64 + mt * 16 + quad * 4 + r;
                int col = col0 + wn * 64 + nt * 16 + l16;
                float v = acc[mt][nt][r];
                if (MODE == 0){
                    if (col < 512){
                        qb[(size_t)row * 512 + col] = f2bs(v * QSCALE);
                    } else if (col < 576){
                        int bb = row >> 11, ii = row & 2047;
                        kb[((size_t)bb * CTXx + ii + 1) * 64 + (col - 512)] = f2bs(v);
                    } else {
                        int bb = row >> 11, ii = row & 2047;
                        vb[((size_t)bb * CTXx + ii + 1) * 64 + (col - 576)] = f2bs(v);
                    }
                } else {
                    C[(size_t)row * 512 + col] = v;
                }
            }
}

// ---------------- MFMA attention ----------------
// Block: (batch b, 16 q-rows) x all 8 heads. M = 128 (m-tile == head-half).
// Wave w owns heads 2w, 2w+1. Key tiles of 64 (33 tiles, tail masked).
// S frags C-layout -> exp (no-max; scores sigma~0.2) -> P via wave-private LDS -> PV MFMA.
__global__ void __launch_bounds__(256, 2) attn_kernel(const short* __restrict__ qb,
                                                      const short* __restrict__ kb,
                                                      const short* __restrict__ vb,
                                                      const int* __restrict__ mask,
                                                      short* __restrict__ ob){
    __shared__ short Ks[64][72];      // [key][d]
    __shared__ short Vt[64][72];      // [d][key]  (transposed)
    __shared__ short Ps[4][32][72];   // per-wave P: [m_local][key]
    __shared__ float validf[64];
    int t = threadIdx.x;
    int lane = t & 63, w = t >> 6;
    int l16 = lane & 15, quad = lane >> 4;
    int b = blockIdx.y, i0 = blockIdx.x * 16;
    // Q frags live in regs whole kernel: A[m=lane&15][k=quad*8+j]
    bf16x8 qf[2][2];
    #pragma unroll
    for (int mt = 0; mt < 2; mt++){
        int h = w * 2 + mt;
        const short* qp = qb + (size_t)(b * Nx + i0 + l16) * 512 + h * 64 + quad * 8;
        qf[mt][0] = *(const bf16x8*)(qp);
        qf[mt][1] = *(const bf16x8*)(qp + 32);
    }
    f32x4 oacc[2][4];
    float lsum[2][4];
    #pragma unroll
    for (int mt = 0; mt < 2; mt++)
        #pragma unroll
        for (int j = 0; j < 4; j++){ oacc[mt][j] = (f32x4){0.f, 0.f, 0.f, 0.f}; lsum[mt][j] = 0.f; }
    int kj = t >> 2, kd = (t & 3) * 16;
    int vj = (t >> 3) * 2, vd = (t & 7) * 8;
    const int* mrow = mask + b * Nx;
    for (int j0 = 0; j0 < 2112; j0 += 64){
        __syncthreads();
        {   // K staging
            int jg = j0 + kj;
            int4 r0 = make_int4(0,0,0,0), r1 = make_int4(0,0,0,0);
            if (jg < CTXx){
                const short* kp = kb + ((size_t)b * CTXx + jg) * 64 + kd;
                r0 = *(const int4*)kp; r1 = *(const int4*)(kp + 8);
            }
            *(int4*)&Ks[kj][kd]     = r0;
            *(int4*)&Ks[kj][kd + 8] = r1;
        }
        {   // V transpose staging (2 keys x 8 dims per thread, short2 writes)
            int jg = j0 + vj;
            int4 r0 = make_int4(0,0,0,0), r1 = make_int4(0,0,0,0);
            if (jg < CTXx){
                const short* vp = vb + ((size_t)b * CTXx + jg) * 64 + vd;
                r0 = *(const int4*)vp;
                if (jg + 1 < CTXx) r1 = *(const int4*)(vp + 64);
            }
            const short* s0 = (const short*)&r0;
            const short* s1 = (const short*)&r1;
            #pragma unroll
            for (int i = 0; i < 8; i++){
                short2v pr; pr[0] = s0[i]; pr[1] = s1[i];
                *(short2v*)&Vt[vd + i][vj] = pr;
            }
        }
        if (t < 64){   // validity multiplier (null key j==0 always valid)
            int jg = j0 + t;
            float vl = (jg == 0) ? 1.f : ((jg < CTXx) ? (mrow[jg - 1] ? 1.f : 0.f) : 0.f);
            validf[t] = vl;
        }
        __syncthreads();
        // S = Q K^T
        f32x4 sf[2][4];
        #pragma unroll
        for (int mt = 0; mt < 2; mt++)
            #pragma unroll
            for (int nt = 0; nt < 4; nt++) sf[mt][nt] = (f32x4){0.f, 0.f, 0.f, 0.f};
        #pragma unroll
        for (int ks = 0; ks < 2; ks++){
            bf16x8 kf[4];
            #pragma unroll
            for (int nt = 0; nt < 4; nt++)
                kf[nt] = *(const bf16x8*)&Ks[nt * 16 + l16][ks * 32 + quad * 8];
            #pragma unroll
            for (int mt = 0; mt < 2; mt++)
                #pragma unroll
                for (int nt = 0; nt < 4; nt++)
                    sf[mt][nt] = __builtin_amdgcn_mfma_f32_16x16x32_bf16(qf[mt][ks], kf[nt], sf[mt][nt], 0, 0, 0);
        }
        // exp + mask + write P (wave-private -> no barrier)
        #pragma unroll
        for (int nt = 0; nt < 4; nt++){
            float vmul = validf[nt * 16 + l16];
            #pragma unroll
            for (int mt = 0; mt < 2; mt++)
                #pragma unroll
                for (int r = 0; r < 4; r++){
                    float p = __expf(sf[mt][nt][r]) * vmul;
                    lsum[mt][r] += p;
                    Ps[w][mt * 16 + quad * 4 + r][nt * 16 + l16] = f2bs(p);
                }
        }
        // O += P V
        #pragma unroll
        for (int ks = 0; ks < 2; ks++){
            bf16x8 vf[4], pf2[2];
            #pragma unroll
            for (int dt = 0; dt < 4; dt++)
                vf[dt] = *(const bf16x8*)&Vt[dt * 16 + l16][ks * 32 + quad * 8];
            #pragma unroll
            for (int mt = 0; mt < 2; mt++)
                pf2[mt] = *(const bf16x8*)&Ps[w][mt * 16 + l16][ks * 32 + quad * 8];
            #pragma unroll
            for (int mt = 0; mt < 2; mt++)
                #pragma unroll
                for (int dt = 0; dt < 4; dt++)
                    oacc[mt][dt] = __builtin_amdgcn_mfma_f32_16x16x32_bf16(pf2[mt], vf[dt], oacc[mt][dt], 0, 0, 0);
        }
    }
    // l reduction across the quad's 16 lanes, then normalize + store
    float linv[2][4];
    #pragma unroll
    for (int mt = 0; mt < 2; mt++)
        #pragma unroll
        for (int r = 0; r < 4; r++){
            float L = lsum[mt][r];
            L += __shfl_xor(L, 1, 64);
            L += __shfl_xor(L, 2, 64);
            L += __shfl_xor(L, 4, 64);
            L += __shfl_xor(L, 8, 64);
            linv[mt][r] = 1.f / L;
        }
    #pragma unroll
    for (int mt = 0; mt < 2; mt++){
        int h = w * 2 + mt;
        #pragma unroll
        for (int r = 0; r < 4; r++){
            int row = i0 + quad * 4 + r;
            short* op = ob + (size_t)(b * Nx + row) * 512 + h * 64;
            #pragma unroll
            for (int dt = 0; dt < 4; dt++)
                op[dt * 16 + l16] = f2bs(oacc[mt][dt][r] * linv[mt][r]);
        }
    }
}

extern "C" void kernel_launch(void* const* d_in, const int* in_sizes, int n_in,
                              void* d_out, int out_size, void* d_ws, size_t ws_size,
                              hipStream_t stream){
    const float* x     = (const float*)d_in[0];
    const int*   mask  = (const int*)  d_in[1];
    const float* gamma = (const float*)d_in[2];
    const float* Wq    = (const float*)d_in[3];
    const float* Wkv   = (const float*)d_in[4];
    const float* nkv   = (const float*)d_in[5];
    const float* Wout  = (const float*)d_in[6];
    const float* og    = (const float*)d_in[7];
    float* out = (float*)d_out;

    short* xnb   = (short*)d_ws;                 // 4194304 shorts
    short* qb    = xnb + (size_t)4194304;        // 4194304
    short* kb    = qb  + (size_t)4194304;        // 524544
    short* vb    = kb  + (size_t)524544;         // 524544
    short* ob    = vb  + (size_t)524544;         // 4194304
    short* Wcat  = ob  + (size_t)4194304;        // 327680
    short* Woutb = Wcat + (size_t)327680;        // 262144
    float* zb    = (float*)d_ws;                 // aliases xnb+qb (dead by gemm_out)

    ln1_kernel  <<<2048, 256, 0, stream>>>(x, gamma, xnb);
    convert_wcat<<<512, 320, 0, stream>>>(Wq, Wkv, Wcat);
    convert_wout<<<1024, 256, 0, stream>>>(Wout, Woutb);
    nullkv_kernel<<<1, 256, 0, stream>>>(nkv, kb, vb);
    gemm_mfma<0><<<dim3(5, 64), 256, 0, stream>>>(xnb, Wcat, 640, qb, kb, vb, nullptr);
    attn_kernel <<<dim3(128, 4), 256, 0, stream>>>(qb, kb, vb, mask, ob);
    gemm_mfma<1><<<dim3(4, 64), 256, 0, stream>>>(ob, Woutb, 512, nullptr, nullptr, nullptr, zb);
    ln2_kernel  <<<2048, 256, 0, stream>>>(zb, og, out);
}

// Round 4
// 200.765 us; speedup vs baseline: 16.0229x; 1.1627x over previous
//
#include <hip/hip_runtime.h>

typedef __attribute__((ext_vector_type(8)))  short bf16x8;   // MFMA A/B frag (4 VGPRs)
typedef __attribute__((ext_vector_type(4)))  float f32x4;    // 16x16 C/D frag
typedef __attribute__((ext_vector_type(16))) float f32x16;   // 32x32 C/D frag
typedef __attribute__((ext_vector_type(4)))  unsigned u32x4;

#define Nx 2048
#define CTXx 2049
#define KCAP 2112          // key capacity: 33 tiles of 64, pad region stays poison (finite) & masked
#define QSCALE 0.125f

__device__ __forceinline__ short f2bs(float x){   // float -> bf16 bits (RNE)
    unsigned u = __builtin_bit_cast(unsigned, x);
    u = (u + 0x7fffu + ((u >> 16) & 1u)) >> 16;
    return (short)u;
}
__device__ __forceinline__ unsigned pack2(float lo, float hi){
    return ((unsigned)(unsigned short)f2bs(hi) << 16) | (unsigned)(unsigned short)f2bs(lo);
}

// ---------------- LN1: fp32 in -> bf16 out, wave per row ----------------
__global__ void __launch_bounds__(256) ln1_kernel(const float* __restrict__ x,
                                                  const float* __restrict__ g,
                                                  short* __restrict__ out){
    int w = threadIdx.x >> 6, lane = threadIdx.x & 63;
    size_t row = (size_t)blockIdx.x * 4 + w;
    const float* xr = x + row * 512 + lane * 8;
    float4 a = *(const float4*)xr;
    float4 b = *(const float4*)(xr + 4);
    float s = a.x + a.y + a.z + a.w + b.x + b.y + b.z + b.w;
    float q = a.x*a.x + a.y*a.y + a.z*a.z + a.w*a.w
            + b.x*b.x + b.y*b.y + b.z*b.z + b.w*b.w;
    #pragma unroll
    for (int m = 1; m < 64; m <<= 1){ s += __shfl_xor(s, m, 64); q += __shfl_xor(q, m, 64); }
    float mu  = s * (1.f / 512.f);
    float var = fmaxf(q * (1.f / 512.f) - mu * mu, 0.f);
    float r   = rsqrtf(var + 1e-5f);
    const float* gr = g + lane * 8;
    float4 g0 = *(const float4*)gr;
    float4 g1 = *(const float4*)(gr + 4);
    bf16x8 o;
    o[0] = f2bs((a.x - mu) * r * g0.x); o[1] = f2bs((a.y - mu) * r * g0.y);
    o[2] = f2bs((a.z - mu) * r * g0.z); o[3] = f2bs((a.w - mu) * r * g0.w);
    o[4] = f2bs((b.x - mu) * r * g1.x); o[5] = f2bs((b.y - mu) * r * g1.y);
    o[6] = f2bs((b.z - mu) * r * g1.z); o[7] = f2bs((b.w - mu) * r * g1.w);
    *(bf16x8*)(out + row * 512 + lane * 8) = o;
}

// ---------------- LN2: fp32 in -> fp32 out, wave per row ----------------
__global__ void __launch_bounds__(256) ln2_kernel(const float* __restrict__ z,
                                                  const float* __restrict__ g,
                                                  float* __restrict__ out){
    int w = threadIdx.x >> 6, lane = threadIdx.x & 63;
    size_t row = (size_t)blockIdx.x * 4 + w;
    const float* xr = z + row * 512 + lane * 8;
    float4 a = *(const float4*)xr;
    float4 b = *(const float4*)(xr + 4);
    float s = a.x + a.y + a.z + a.w + b.x + b.y + b.z + b.w;
    float q = a.x*a.x + a.y*a.y + a.z*a.z + a.w*a.w
            + b.x*b.x + b.y*b.y + b.z*b.z + b.w*b.w;
    #pragma unroll
    for (int m = 1; m < 64; m <<= 1){ s += __shfl_xor(s, m, 64); q += __shfl_xor(q, m, 64); }
    float mu  = s * (1.f / 512.f);
    float var = fmaxf(q * (1.f / 512.f) - mu * mu, 0.f);
    float r   = rsqrtf(var + 1e-5f);
    const float* gr = g + lane * 8;
    float4 g0 = *(const float4*)gr;
    float4 g1 = *(const float4*)(gr + 4);
    float4 o0, o1;
    o0.x = (a.x - mu) * r * g0.x; o0.y = (a.y - mu) * r * g0.y;
    o0.z = (a.z - mu) * r * g0.z; o0.w = (a.w - mu) * r * g0.w;
    o1.x = (b.x - mu) * r * g1.x; o1.y = (b.y - mu) * r * g1.y;
    o1.z = (b.z - mu) * r * g1.z; o1.w = (b.w - mu) * r * g1.w;
    float* op = out + row * 512 + lane * 8;
    *(float4*)op = o0; *(float4*)(op + 4) = o1;
}

// ---------------- prep: transposed bf16 weights + null K/V row (merged) ----------------
// WcatT[n=640][k=512] = [Wq|Wkv]^T ; WoutT[n=512][k=512] = Wout^T
__global__ void __launch_bounds__(256) prep_kernel(const float* __restrict__ Wq,
                                                   const float* __restrict__ Wkv,
                                                   const float* __restrict__ Wout,
                                                   const float* __restrict__ nkv,
                                                   short* __restrict__ WcatT,
                                                   short* __restrict__ WoutT,
                                                   short* __restrict__ kb,
                                                   short* __restrict__ vbt){
    int t = threadIdx.x;
    if (blockIdx.x == 2304){   // null K/V row (key 0, all batches)
        int b = t >> 6, d = t & 63;
        kb[((size_t)b * KCAP) * 64 + d] = f2bs(nkv[d]);
        vbt[((size_t)b * 64 + d) * KCAP + 0] = f2bs(nkv[64 + d]);
        return;
    }
    int idx = blockIdx.x * 256 + t;
    if (idx < 327680){
        int n = idx >> 9, k = idx & 511;
        float v = (n < 512) ? Wq[(size_t)k * 512 + n] : Wkv[(size_t)k * 128 + (n - 512)];
        WcatT[idx] = f2bs(v);
    } else {
        int j = idx - 327680;
        int n = j >> 9, k = j & 511;
        WoutT[j] = f2bs(Wout[(size_t)k * 512 + n]);
    }
}

// ---------------- MFMA GEMM: 128x128 tile, BK=64, 4 waves 2x2, B pre-transposed ----------------
// MODE 0: C = xn @ [Wq|Wkv] (N=640): q-scale + K scatter + V^T scatter epilogue (bf16)
// MODE 1: C = ob @ Wout (N=512): fp32 out
template<int MODE>
__global__ void __launch_bounds__(256, 2) gemm_mfma(const short* __restrict__ A,
                                                    const short* __restrict__ BwT,
                                                    short* __restrict__ qb,
                                                    short* __restrict__ kb,
                                                    short* __restrict__ vbt,
                                                    float* __restrict__ C){
    __shared__ short As[128][72];   // [m][k]
    __shared__ short Bs[128][72];   // [n][k]
    int t = threadIdx.x;
    int lane = t & 63, w = t >> 6;
    int l16 = lane & 15, quad = lane >> 4;
    int wm = w & 1, wn = w >> 1;
    int row0 = blockIdx.y * 128, col0 = blockIdx.x * 128;
    f32x4 acc[4][4];
    #pragma unroll
    for (int i = 0; i < 4; i++)
        #pragma unroll
        for (int j = 0; j < 4; j++) acc[i][j] = (f32x4){0.f, 0.f, 0.f, 0.f};
    int ar = t >> 1, ak = (t & 1) * 32;
    for (int k0 = 0; k0 < 512; k0 += 64){
        __syncthreads();
        {   // A staging: 32 shorts/thread
            const short* ap = A + (size_t)(row0 + ar) * 512 + k0 + ak;
            int4 a0 = *(const int4*)(ap);
            int4 a1 = *(const int4*)(ap + 8);
            int4 a2 = *(const int4*)(ap + 16);
            int4 a3 = *(const int4*)(ap + 24);
            *(int4*)&As[ar][ak]      = a0;
            *(int4*)&As[ar][ak + 8]  = a1;
            *(int4*)&As[ar][ak + 16] = a2;
            *(int4*)&As[ar][ak + 24] = a3;
        }
        {   // B staging: direct copy from transposed weights
            const short* bp = BwT + (size_t)(col0 + ar) * 512 + k0 + ak;
            int4 b0 = *(const int4*)(bp);
            int4 b1 = *(const int4*)(bp + 8);
            int4 b2 = *(const int4*)(bp + 16);
            int4 b3 = *(const int4*)(bp + 24);
            *(int4*)&Bs[ar][ak]      = b0;
            *(int4*)&Bs[ar][ak + 8]  = b1;
            *(int4*)&Bs[ar][ak + 16] = b2;
            *(int4*)&Bs[ar][ak + 24] = b3;
        }
        __syncthreads();
        #pragma unroll
        for (int ks = 0; ks < 2; ks++){
            bf16x8 af[4], bfr[4];
            #pragma unroll
            for (int mt = 0; mt < 4; mt++)
                af[mt] = *(const bf16x8*)&As[wm * 64 + mt * 16 + l16][ks * 32 + quad * 8];
            #pragma unroll
            for (int nt = 0; nt < 4; nt++)
                bfr[nt] = *(const bf16x8*)&Bs[wn * 64 + nt * 16 + l16][ks * 32 + quad * 8];
            #pragma unroll
            for (int mt = 0; mt < 4; mt++)
                #pragma unroll
                for (int nt = 0; nt < 4; nt++)
                    acc[mt][nt] = __builtin_amdgcn_mfma_f32_16x16x32_bf16(af[mt], bfr[nt], acc[mt][nt], 0, 0, 0);
        }
    }
    #pragma unroll
    for (int mt = 0; mt < 4; mt++)
        #pragma unroll
        for (int nt = 0; nt < 4; nt++)
            #pragma unroll
            for (int r = 0; r < 4; r++){
                int row = row0 + wm * 64 + mt * 16 + quad * 4 + r;
                int col = col0 + wn * 64 + nt * 16 + l16;
                float v = acc[mt][nt][r];
                if (MODE == 0){
                    int bb = row >> 11, ii = row & 2047;
                    if (col < 512){
                        qb[(size_t)row * 512 + col] = f2bs(v * QSCALE);
                    } else if (col < 576){
                        kb[((size_t)bb * KCAP + ii + 1) * 64 + (col - 512)] = f2bs(v);
                    } else {
                        vbt[((size_t)bb * 64 + (col - 576)) * KCAP + ii + 1] = f2bs(v);
                    }
                } else {
                    C[(size_t)row * 512 + col] = v;
                }
            }
}

// ---------------- MFMA attention, 32x32x16, S^T scheme ----------------
// Block = (batch, 16 q-rows) x 8 heads; wave w = heads 2w,2w+1 (n=32 = 2 heads x 16 rows).
// S^T = K.Q^T  (A=K, B=Q): C-layout col=lane&31=head-row -> exp/mask/pack in registers;
// P -> PV A-operand needs only a lane^32 exchange. V pre-transposed globally.
__global__ void __launch_bounds__(256, 2) attn_kernel(const short* __restrict__ qb,
                                                      const short* __restrict__ kb,
                                                      const short* __restrict__ vbt,
                                                      const int* __restrict__ mask,
                                                      short* __restrict__ ob){
    __shared__ short Ks[64][72];   // [key][d]
    __shared__ short Vt[64][72];   // [d][key]
    __shared__ float Ls[4][32];
    int t = threadIdx.x;
    int lane = t & 63, w = t >> 6;
    int n32 = lane & 31, hb = lane >> 5;
    int b = blockIdx.y, i0 = blockIdx.x * 16;
    int head = 2 * w + (n32 >> 4), row = i0 + (n32 & 15);
    // Q frags (B-operand): B[k=8hb+j][n=n32] = Q[row][head*64 + ks*16 + 8hb + j]
    bf16x8 qf[4];
    {
        const short* qp = qb + ((size_t)(b * Nx + row)) * 512 + head * 64 + hb * 8;
        #pragma unroll
        for (int ks = 0; ks < 4; ks++) qf[ks] = *(const bf16x8*)(qp + ks * 16);
    }
    f32x16 oacc[2];
    #pragma unroll
    for (int i = 0; i < 2; i++)
        #pragma unroll
        for (int j = 0; j < 16; j++) oacc[i][j] = 0.f;
    float lsum = 0.f;

    int skey = t >> 2, sd = (t & 3) * 16;   // K staging: 64 keys x 64 d
    int vd   = t >> 2, vk = (t & 3) * 16;   // V staging: 64 d x 64 keys
    const short* kgp = kb  + (size_t)b * KCAP * 64 + skey * 64 + sd;
    const short* vgp = vbt + ((size_t)b * 64 + vd) * KCAP + vk;
    const int* mrow = mask + b * Nx;

    int4 pk0, pk1, pv0, pv1;
    int mok;
    {   // prefetch tile 0 (buffers padded to KCAP: no bounds checks on K/V)
        pk0 = *(const int4*)(kgp);
        pk1 = *(const int4*)(kgp + 8);
        pv0 = *(const int4*)(vgp);
        pv1 = *(const int4*)(vgp + 8);
        int jg = lane;
        mok = (jg == 0) ? 1 : ((jg < CTXx) ? mrow[jg - 1] : 0);
    }
    for (int j0 = 0; j0 < KCAP; j0 += 64){
        __syncthreads();
        *(int4*)&Ks[skey][sd]     = pk0;
        *(int4*)&Ks[skey][sd + 8] = pk1;
        *(int4*)&Vt[vd][vk]       = pv0;
        *(int4*)&Vt[vd][vk + 8]   = pv1;
        unsigned long long bal = __ballot(mok != 0);
        __syncthreads();
        int jn = j0 + 64;
        if (jn < KCAP){   // prefetch next tile
            pk0 = *(const int4*)(kgp + (size_t)jn * 64);
            pk1 = *(const int4*)(kgp + (size_t)jn * 64 + 8);
            pv0 = *(const int4*)(vgp + jn);
            pv1 = *(const int4*)(vgp + jn + 8);
            int jg = jn + lane;
            mok = (jg < CTXx) ? mrow[jg - 1] : 0;
        }
        // S^T = K.Q^T : A=K-frag, B=Q-frag
        f32x16 sf[2];
        #pragma unroll
        for (int i = 0; i < 2; i++)
            #pragma unroll
            for (int j = 0; j < 16; j++) sf[i][j] = 0.f;
        #pragma unroll
        for (int ks = 0; ks < 4; ks++){
            #pragma unroll
            for (int kt = 0; kt < 2; kt++){
                bf16x8 kf = *(const bf16x8*)&Ks[kt * 32 + n32][ks * 16 + hb * 8];
                sf[kt] = __builtin_amdgcn_mfma_f32_32x32x16_bf16(kf, qf[ks], sf[kt], 0, 0, 0);
            }
        }
        // exp + mask + pack (all in registers)
        // key(kt, reg, hb) = kt*32 + 8*(reg>>2) + 4*hb + (reg&3)
        unsigned mlo = (unsigned)(bal >> (4 * hb));
        unsigned mhi = (unsigned)(bal >> (32 + 4 * hb));
        unsigned pg[8][2];
        #pragma unroll
        for (int kt = 0; kt < 2; kt++){
            unsigned mm = kt ? mhi : mlo;
            #pragma unroll
            for (int g4 = 0; g4 < 4; g4++){
                float p[4];
                #pragma unroll
                for (int tt = 0; tt < 4; tt++){
                    float e = __expf(sf[kt][g4 * 4 + tt]);
                    p[tt] = ((mm >> (8 * g4 + tt)) & 1u) ? e : 0.f;
                    lsum += p[tt];
                }
                pg[kt * 4 + g4][0] = pack2(p[0], p[1]);
                pg[kt * 4 + g4][1] = pack2(p[2], p[3]);
            }
        }
        // PV: A-frag keys s*16+8hb+0..7 = [hb0-half's pg[2s+hb], hb1-half's pg[2s+hb]]
        #pragma unroll
        for (int s = 0; s < 4; s++){
            unsigned slo = hb ? pg[2 * s][0] : pg[2 * s + 1][0];   // send what partner needs
            unsigned shi = hb ? pg[2 * s][1] : pg[2 * s + 1][1];
            unsigned rlo = (unsigned)__shfl_xor((int)slo, 32, 64);
            unsigned rhi = (unsigned)__shfl_xor((int)shi, 32, 64);
            unsigned q0 = hb ? rlo : pg[2 * s][0];
            unsigned q1 = hb ? rhi : pg[2 * s][1];
            unsigned q2 = hb ? pg[2 * s + 1][0] : rlo;
            unsigned q3 = hb ? pg[2 * s + 1][1] : rhi;
            bf16x8 pa = __builtin_bit_cast(bf16x8, (u32x4){q0, q1, q2, q3});
            #pragma unroll
            for (int nt = 0; nt < 2; nt++){
                bf16x8 vf = *(const bf16x8*)&Vt[nt * 32 + n32][s * 16 + hb * 8];
                oacc[nt] = __builtin_amdgcn_mfma_f32_32x32x16_bf16(pa, vf, oacc[nt], 0, 0, 0);
            }
        }
    }
    // softmax denominator: partner half covers the other 32 keys of each tile
    float L = lsum + __shfl_xor(lsum, 32, 64);
    if (hb == 0) Ls[w][n32] = 1.f / L;
    __syncthreads();
    #pragma unroll
    for (int nt = 0; nt < 2; nt++)
        #pragma unroll
        for (int r = 0; r < 16; r++){
            int hr = (r & 3) + 8 * (r >> 2) + 4 * hb;
            float o = oacc[nt][r] * Ls[w][hr];
            int grow = i0 + (hr & 15);
            int ghead = 2 * w + (hr >> 4);
            ob[((size_t)(b * Nx + grow)) * 512 + ghead * 64 + nt * 32 + n32] = f2bs(o);
        }
}

extern "C" void kernel_launch(void* const* d_in, const int* in_sizes, int n_in,
                              void* d_out, int out_size, void* d_ws, size_t ws_size,
                              hipStream_t stream){
    const float* x     = (const float*)d_in[0];
    const int*   mask  = (const int*)  d_in[1];
    const float* gamma = (const float*)d_in[2];
    const float* Wq    = (const float*)d_in[3];
    const float* Wkv   = (const float*)d_in[4];
    const float* nkv   = (const float*)d_in[5];
    const float* Wout  = (const float*)d_in[6];
    const float* og    = (const float*)d_in[7];
    float* out = (float*)d_out;

    short* xnb   = (short*)d_ws;                 // 4194304
    short* qb    = xnb + (size_t)4194304;        // 4194304
    short* kb    = qb  + (size_t)4194304;        // 4*KCAP*64 = 540672
    short* vbt   = kb  + (size_t)540672;         // 540672
    short* ob    = vbt + (size_t)540672;         // 4194304
    short* WcatT = ob  + (size_t)4194304;        // 327680
    short* WoutT = WcatT + (size_t)327680;       // 262144
    float* zb    = (float*)d_ws;                 // aliases xnb+qb (dead by gemm_out)

    ln1_kernel  <<<2048, 256, 0, stream>>>(x, gamma, xnb);
    prep_kernel <<<2305, 256, 0, stream>>>(Wq, Wkv, Wout, nkv, WcatT, WoutT, kb, vbt);
    gemm_mfma<0><<<dim3(5, 64), 256, 0, stream>>>(xnb, WcatT, qb, kb, vbt, nullptr);
    attn_kernel <<<dim3(128, 4), 256, 0, stream>>>(qb, kb, vbt, mask, ob);
    gemm_mfma<1><<<dim3(4, 64), 256, 0, stream>>>(ob, WoutT, nullptr, nullptr, nullptr, zb);
    ln2_kernel  <<<2048, 256, 0, stream>>>(zb, og, out);
}

// Round 5
// 186.051 us; speedup vs baseline: 17.2901x; 1.0791x over previous
//
#include <hip/hip_runtime.h>

typedef __attribute__((ext_vector_type(8)))  short bf16x8;   // MFMA A/B frag (4 VGPRs)
typedef __attribute__((ext_vector_type(4)))  float f32x4;    // 16x16 C/D frag
typedef __attribute__((ext_vector_type(16))) float f32x16;   // 32x32 C/D frag
typedef __attribute__((ext_vector_type(4)))  unsigned u32x4;

#define Nx 2048
#define CTXx 2049
#define KCAP 2112          // 33 tiles of 64; pad keys stay poison (finite bf16) & masked
#define QSCALE 0.18033688f // 0.125 * log2(e): softmax computed as 2^(S*log2e) = e^S

__device__ __forceinline__ short f2bs(float x){   // float -> bf16 bits (RNE)
    unsigned u = __builtin_bit_cast(unsigned, x);
    u = (u + 0x7fffu + ((u >> 16) & 1u)) >> 16;
    return (short)u;
}
// truncating pack: (hi16 of b)<<16 | (hi16 of a) — 1 v_perm_b32
__device__ __forceinline__ unsigned pack_trunc(float a, float b){
    return __builtin_amdgcn_perm(__builtin_bit_cast(unsigned, b),
                                 __builtin_bit_cast(unsigned, a), 0x07060302u);
}

// ---------------- LN1: fp32 in -> bf16 out, wave per row ----------------
__global__ void __launch_bounds__(256) ln1_kernel(const float* __restrict__ x,
                                                  const float* __restrict__ g,
                                                  short* __restrict__ out){
    int w = threadIdx.x >> 6, lane = threadIdx.x & 63;
    size_t row = (size_t)blockIdx.x * 4 + w;
    const float* xr = x + row * 512 + lane * 8;
    float4 a = *(const float4*)xr;
    float4 b = *(const float4*)(xr + 4);
    float s = a.x + a.y + a.z + a.w + b.x + b.y + b.z + b.w;
    float q = a.x*a.x + a.y*a.y + a.z*a.z + a.w*a.w
            + b.x*b.x + b.y*b.y + b.z*b.z + b.w*b.w;
    #pragma unroll
    for (int m = 1; m < 64; m <<= 1){ s += __shfl_xor(s, m, 64); q += __shfl_xor(q, m, 64); }
    float mu  = s * (1.f / 512.f);
    float var = fmaxf(q * (1.f / 512.f) - mu * mu, 0.f);
    float r   = rsqrtf(var + 1e-5f);
    const float* gr = g + lane * 8;
    float4 g0 = *(const float4*)gr;
    float4 g1 = *(const float4*)(gr + 4);
    bf16x8 o;
    o[0] = f2bs((a.x - mu) * r * g0.x); o[1] = f2bs((a.y - mu) * r * g0.y);
    o[2] = f2bs((a.z - mu) * r * g0.z); o[3] = f2bs((a.w - mu) * r * g0.w);
    o[4] = f2bs((b.x - mu) * r * g1.x); o[5] = f2bs((b.y - mu) * r * g1.y);
    o[6] = f2bs((b.z - mu) * r * g1.z); o[7] = f2bs((b.w - mu) * r * g1.w);
    *(bf16x8*)(out + row * 512 + lane * 8) = o;
}

// ---------------- LN2: fp32 in -> fp32 out, wave per row ----------------
__global__ void __launch_bounds__(256) ln2_kernel(const float* __restrict__ z,
                                                  const float* __restrict__ g,
                                                  float* __restrict__ out){
    int w = threadIdx.x >> 6, lane = threadIdx.x & 63;
    size_t row = (size_t)blockIdx.x * 4 + w;
    const float* xr = z + row * 512 + lane * 8;
    float4 a = *(const float4*)xr;
    float4 b = *(const float4*)(xr + 4);
    float s = a.x + a.y + a.z + a.w + b.x + b.y + b.z + b.w;
    float q = a.x*a.x + a.y*a.y + a.z*a.z + a.w*a.w
            + b.x*b.x + b.y*b.y + b.z*b.z + b.w*b.w;
    #pragma unroll
    for (int m = 1; m < 64; m <<= 1){ s += __shfl_xor(s, m, 64); q += __shfl_xor(q, m, 64); }
    float mu  = s * (1.f / 512.f);
    float var = fmaxf(q * (1.f / 512.f) - mu * mu, 0.f);
    float r   = rsqrtf(var + 1e-5f);
    const float* gr = g + lane * 8;
    float4 g0 = *(const float4*)gr;
    float4 g1 = *(const float4*)(gr + 4);
    float4 o0, o1;
    o0.x = (a.x - mu) * r * g0.x; o0.y = (a.y - mu) * r * g0.y;
    o0.z = (a.z - mu) * r * g0.z; o0.w = (a.w - mu) * r * g0.w;
    o1.x = (b.x - mu) * r * g1.x; o1.y = (b.y - mu) * r * g1.y;
    o1.z = (b.z - mu) * r * g1.z; o1.w = (b.w - mu) * r * g1.w;
    float* op = out + row * 512 + lane * 8;
    *(float4*)op = o0; *(float4*)(op + 4) = o1;
}

// ---------------- prep: LDS-tiled coalesced transpose + null K/V ----------------
// blocks 0..79: WcatT (640x512) 64x64 tiles; 80..143: WoutT (512x512); 144: null K/V
__global__ void __launch_bounds__(256) prep_kernel(const float* __restrict__ Wq,
                                                   const float* __restrict__ Wkv,
                                                   const float* __restrict__ Wout,
                                                   const float* __restrict__ nkv,
                                                   short* __restrict__ WcatT,
                                                   short* __restrict__ WoutT,
                                                   short* __restrict__ kb,
                                                   short* __restrict__ vbt){
    int bid = blockIdx.x, t = threadIdx.x;
    if (bid == 144){   // null K/V row (key 0, all batches)
        int b = t >> 6, d = t & 63;
        kb[((size_t)b * KCAP) * 64 + d] = f2bs(nkv[d]);
        vbt[((size_t)b * 64 + d) * KCAP + 0] = f2bs(nkv[64 + d]);
        return;
    }
    __shared__ float ls[64][65];   // [n_local][k_local]
    bool isOut = (bid >= 80);
    int b2 = isOut ? bid - 80 : bid;
    int ntile = isOut ? (b2 & 7) : (b2 % 10);
    int ktile = isOut ? (b2 >> 3) : (b2 / 10);
    int n0 = ntile * 64, k0 = ktile * 64;
    #pragma unroll
    for (int rr = 0; rr < 64; rr += 16){   // coalesced float4 reads of W[k][n]
        int r = rr + (t >> 4), c = (t & 15) * 4;
        float4 v;
        if (isOut)            v = *(const float4*)(Wout + (size_t)(k0 + r) * 512 + n0 + c);
        else if (n0 < 512)    v = *(const float4*)(Wq   + (size_t)(k0 + r) * 512 + n0 + c);
        else                  v = *(const float4*)(Wkv  + (size_t)(k0 + r) * 128 + (n0 - 512) + c);
        ls[c + 0][r] = v.x; ls[c + 1][r] = v.y; ls[c + 2][r] = v.z; ls[c + 3][r] = v.w;
    }
    __syncthreads();
    int rn = t >> 2, kc = (t & 3) * 16;    // coalesced 32B bf16 writes of W^T[n][k]
    short tmp[16];
    #pragma unroll
    for (int j = 0; j < 16; j++) tmp[j] = f2bs(ls[rn][kc + j]);
    short* dst = (isOut ? WoutT : WcatT) + (size_t)(n0 + rn) * 512 + k0 + kc;
    *(int4*)dst       = *(int4*)&tmp[0];
    *(int4*)(dst + 8) = *(int4*)&tmp[8];
}

// ---------------- MFMA GEMM: 128x128 tile, BK=64, 4 waves 2x2, B pre-transposed ----------------
// MODE 0: C = xn @ [Wq|Wkv] (N=640): q-scale(incl log2e) + K scatter + V^T scatter (bf16)
// MODE 1: C = ob @ Wout (N=512): fp32 out
template<int MODE>
__global__ void __launch_bounds__(256, 2) gemm_mfma(const short* __restrict__ A,
                                                    const short* __restrict__ BwT,
                                                    short* __restrict__ qb,
                                                    short* __restrict__ kb,
                                                    short* __restrict__ vbt,
                                                    float* __restrict__ C){
    __shared__ short As[128][72];   // [m][k]
    __shared__ short Bs[128][72];   // [n][k]
    int t = threadIdx.x;
    int lane = t & 63, w = t >> 6;
    int l16 = lane & 15, quad = lane >> 4;
    int wm = w & 1, wn = w >> 1;
    int row0 = blockIdx.y * 128, col0 = blockIdx.x * 128;
    f32x4 acc[4][4];
    #pragma unroll
    for (int i = 0; i < 4; i++)
        #pragma unroll
        for (int j = 0; j < 4; j++) acc[i][j] = (f32x4){0.f, 0.f, 0.f, 0.f};
    int ar = t >> 1, ak = (t & 1) * 32;
    for (int k0 = 0; k0 < 512; k0 += 64){
        __syncthreads();
        {   // A staging: 32 shorts/thread
            const short* ap = A + (size_t)(row0 + ar) * 512 + k0 + ak;
            int4 a0 = *(const int4*)(ap);
            int4 a1 = *(const int4*)(ap + 8);
            int4 a2 = *(const int4*)(ap + 16);
            int4 a3 = *(const int4*)(ap + 24);
            *(int4*)&As[ar][ak]      = a0;
            *(int4*)&As[ar][ak + 8]  = a1;
            *(int4*)&As[ar][ak + 16] = a2;
            *(int4*)&As[ar][ak + 24] = a3;
        }
        {   // B staging: direct copy from transposed weights
            const short* bp = BwT + (size_t)(col0 + ar) * 512 + k0 + ak;
            int4 b0 = *(const int4*)(bp);
            int4 b1 = *(const int4*)(bp + 8);
            int4 b2 = *(const int4*)(bp + 16);
            int4 b3 = *(const int4*)(bp + 24);
            *(int4*)&Bs[ar][ak]      = b0;
            *(int4*)&Bs[ar][ak + 8]  = b1;
            *(int4*)&Bs[ar][ak + 16] = b2;
            *(int4*)&Bs[ar][ak + 24] = b3;
        }
        __syncthreads();
        #pragma unroll
        for (int ks = 0; ks < 2; ks++){
            bf16x8 af[4], bfr[4];
            #pragma unroll
            for (int mt = 0; mt < 4; mt++)
                af[mt] = *(const bf16x8*)&As[wm * 64 + mt * 16 + l16][ks * 32 + quad * 8];
            #pragma unroll
            for (int nt = 0; nt < 4; nt++)
                bfr[nt] = *(const bf16x8*)&Bs[wn * 64 + nt * 16 + l16][ks * 32 + quad * 8];
            #pragma unroll
            for (int mt = 0; mt < 4; mt++)
                #pragma unroll
                for (int nt = 0; nt < 4; nt++)
                    acc[mt][nt] = __builtin_amdgcn_mfma_f32_16x16x32_bf16(af[mt], bfr[nt], acc[mt][nt], 0, 0, 0);
        }
    }
    #pragma unroll
    for (int mt = 0; mt < 4; mt++)
        #pragma unroll
        for (int nt = 0; nt < 4; nt++)
            #pragma unroll
            for (int r = 0; r < 4; r++){
                int row = row0 + wm * 64 + mt * 16 + quad * 4 + r;
                int col = col0 + wn * 64 + nt * 16 + l16;
                float v = acc[mt][nt][r];
                if (MODE == 0){
                    int bb = row >> 11, ii = row & 2047;
                    if (col < 512){
                        qb[(size_t)row * 512 + col] = f2bs(v * QSCALE);
                    } else if (col < 576){
                        kb[((size_t)bb * KCAP + ii + 1) * 64 + (col - 512)] = f2bs(v);
                    } else {
                        vbt[((size_t)bb * 64 + (col - 576)) * KCAP + ii + 1] = f2bs(v);
                    }
                } else {
                    C[(size_t)row * 512 + col] = v;
                }
            }
}

// ---------------- MFMA attention, 32x32x16, S^T scheme, bit-swapped V ----------------
// Block = (batch, 16 q-rows) x 8 heads; wave w = heads 2w,2w+1 (n=32 = 2 heads x 16 rows).
// S^T = K.Q^T (A=K, B=Q): C-layout col=head-row -> exp/mask/pack all in registers.
// P->PV A-operand mismatch is exactly key-index bit2<->bit3; V is staged with key columns
// bit-swapped (free dword shuffle of the two staging int4s), so PV consumes pg directly.
__global__ void __launch_bounds__(256, 2) attn_kernel(const short* __restrict__ qb,
                                                      const short* __restrict__ kb,
                                                      const short* __restrict__ vbt,
                                                      const int* __restrict__ mask,
                                                      short* __restrict__ ob){
    __shared__ short Ks[64][72];   // [key][d]
    __shared__ short Vt[64][72];   // [d][key], key columns bit2<->bit3 swapped
    __shared__ float Ls[4][32];
    int t = threadIdx.x;
    int lane = t & 63, w = t >> 6;
    int n32 = lane & 31, hb = lane >> 5;
    int b = blockIdx.y, i0 = blockIdx.x * 16;
    int head = 2 * w + (n32 >> 4), row = i0 + (n32 & 15);
    // Q frags (B-operand): B[k=8hb+j][n=n32]
    bf16x8 qf[4];
    {
        const short* qp = qb + ((size_t)(b * Nx + row)) * 512 + head * 64 + hb * 8;
        #pragma unroll
        for (int ks = 0; ks < 4; ks++) qf[ks] = *(const bf16x8*)(qp + ks * 16);
    }
    f32x16 oacc[2];
    #pragma unroll
    for (int i = 0; i < 2; i++)
        #pragma unroll
        for (int j = 0; j < 16; j++) oacc[i][j] = 0.f;
    float lsum = 0.f;

    int skey = t >> 2, sd = (t & 3) * 16;   // K staging: 64 keys x 64 d
    int vd   = t >> 2, vk = (t & 3) * 16;   // V staging: 64 d x 64 keys
    const short* kgp = kb  + (size_t)b * KCAP * 64 + skey * 64 + sd;
    const short* vgp = vbt + ((size_t)b * 64 + vd) * KCAP + vk;
    const int* mrow = mask + b * Nx;

    int4 pk0, pk1, pv0, pv1;
    int mok;
    {   // prefetch tile 0 (buffers padded to KCAP: no bounds checks on K/V)
        pk0 = *(const int4*)(kgp);
        pk1 = *(const int4*)(kgp + 8);
        pv0 = *(const int4*)(vgp);
        pv1 = *(const int4*)(vgp + 8);
        int jg = lane;
        mok = (jg == 0) ? 1 : ((jg < CTXx) ? mrow[jg - 1] : 0);
    }
    for (int j0 = 0; j0 < KCAP; j0 += 64){
        __syncthreads();
        *(int4*)&Ks[skey][sd]     = pk0;
        *(int4*)&Ks[skey][sd + 8] = pk1;
        // bit2<->bit3 key permutation == swap middle dwords of the two int4s
        *(int4*)&Vt[vd][vk]       = make_int4(pv0.x, pv0.y, pv1.x, pv1.y);
        *(int4*)&Vt[vd][vk + 8]   = make_int4(pv0.z, pv0.w, pv1.z, pv1.w);
        unsigned long long bal = __ballot(mok != 0);
        __syncthreads();
        int jn = j0 + 64;
        if (jn < KCAP){   // prefetch next tile
            pk0 = *(const int4*)(kgp + (size_t)jn * 64);
            pk1 = *(const int4*)(kgp + (size_t)jn * 64 + 8);
            pv0 = *(const int4*)(vgp + jn);
            pv1 = *(const int4*)(vgp + jn + 8);
            int jg = jn + lane;
            mok = (jg < CTXx) ? mrow[jg - 1] : 0;
        }
        // S^T = K.Q^T : A=K-frag, B=Q-frag
        f32x16 sf[2];
        #pragma unroll
        for (int i = 0; i < 2; i++)
            #pragma unroll
            for (int j = 0; j < 16; j++) sf[i][j] = 0.f;
        #pragma unroll
        for (int ks = 0; ks < 4; ks++){
            #pragma unroll
            for (int kt = 0; kt < 2; kt++){
                bf16x8 kf = *(const bf16x8*)&Ks[kt * 32 + n32][ks * 16 + hb * 8];
                sf[kt] = __builtin_amdgcn_mfma_f32_32x32x16_bf16(kf, qf[ks], sf[kt], 0, 0, 0);
            }
        }
        // exp2 + mask + truncating pack (all in registers)
        // key(kt, reg, hb) = kt*32 + 8*(reg>>2) + 4*hb + (reg&3)
        unsigned mlo = (unsigned)(bal >> (4 * hb));
        unsigned mhi = (unsigned)(bal >> (32 + 4 * hb));
        unsigned pg[8][2];
        #pragma unroll
        for (int kt = 0; kt < 2; kt++){
            unsigned mm = kt ? mhi : mlo;
            #pragma unroll
            for (int g4 = 0; g4 < 4; g4++){
                float p[4];
                #pragma unroll
                for (int tt = 0; tt < 4; tt++){
                    float e = __builtin_amdgcn_exp2f(sf[kt][g4 * 4 + tt]);
                    p[tt] = ((mm >> (8 * g4 + tt)) & 1u) ? e : 0.f;
                    lsum += p[tt];
                }
                pg[kt * 4 + g4][0] = pack_trunc(p[0], p[1]);
                pg[kt * 4 + g4][1] = pack_trunc(p[2], p[3]);
            }
        }
        // PV: pa is lane-local (V columns pre-permuted to match pg's key order)
        #pragma unroll
        for (int s = 0; s < 4; s++){
            bf16x8 pa = __builtin_bit_cast(bf16x8,
                (u32x4){pg[2 * s][0], pg[2 * s][1], pg[2 * s + 1][0], pg[2 * s + 1][1]});
            #pragma unroll
            for (int nt = 0; nt < 2; nt++){
                bf16x8 vf = *(const bf16x8*)&Vt[nt * 32 + n32][s * 16 + hb * 8];
                oacc[nt] = __builtin_amdgcn_mfma_f32_32x32x16_bf16(pa, vf, oacc[nt], 0, 0, 0);
            }
        }
    }
    // softmax denominator: partner half covers the other 32 keys of each tile
    float L = lsum + __shfl_xor(lsum, 32, 64);
    if (hb == 0) Ls[w][n32] = 1.f / L;
    __syncthreads();
    #pragma unroll
    for (int nt = 0; nt < 2; nt++)
        #pragma unroll
        for (int r = 0; r < 16; r++){
            int hr = (r & 3) + 8 * (r >> 2) + 4 * hb;
            float o = oacc[nt][r] * Ls[w][hr];
            int grow = i0 + (hr & 15);
            int ghead = 2 * w + (hr >> 4);
            ob[((size_t)(b * Nx + grow)) * 512 + ghead * 64 + nt * 32 + n32] = f2bs(o);
        }
}

extern "C" void kernel_launch(void* const* d_in, const int* in_sizes, int n_in,
                              void* d_out, int out_size, void* d_ws, size_t ws_size,
                              hipStream_t stream){
    const float* x     = (const float*)d_in[0];
    const int*   mask  = (const int*)  d_in[1];
    const float* gamma = (const float*)d_in[2];
    const float* Wq    = (const float*)d_in[3];
    const float* Wkv   = (const float*)d_in[4];
    const float* nkv   = (const float*)d_in[5];
    const float* Wout  = (const float*)d_in[6];
    const float* og    = (const float*)d_in[7];
    float* out = (float*)d_out;

    short* xnb   = (short*)d_ws;                 // 4194304
    short* qb    = xnb + (size_t)4194304;        // 4194304
    short* kb    = qb  + (size_t)4194304;        // 4*KCAP*64 = 540672
    short* vbt   = kb  + (size_t)540672;         // 540672
    short* ob    = vbt + (size_t)540672;         // 4194304
    short* WcatT = ob  + (size_t)4194304;        // 327680
    short* WoutT = WcatT + (size_t)327680;       // 262144
    float* zb    = (float*)d_ws;                 // aliases xnb+qb (dead by gemm_out)

    ln1_kernel  <<<2048, 256, 0, stream>>>(x, gamma, xnb);
    prep_kernel <<<145, 256, 0, stream>>>(Wq, Wkv, Wout, nkv, WcatT, WoutT, kb, vbt);
    gemm_mfma<0><<<dim3(5, 64), 256, 0, stream>>>(xnb, WcatT, qb, kb, vbt, nullptr);
    attn_kernel <<<dim3(128, 4), 256, 0, stream>>>(qb, kb, vbt, mask, ob);
    gemm_mfma<1><<<dim3(4, 64), 256, 0, stream>>>(ob, WoutT, nullptr, nullptr, nullptr, zb);
    ln2_kernel  <<<2048, 256, 0, stream>>>(zb, og, out);
}